// Round 3
// baseline (44.402 us; speedup 1.0000x reference)
//
#include <hip/hip_runtime.h>
#include <math.h>

// Problem constants (match reference)
constexpr int B = 32;
constexpr int N = 1024;
constexpr int S = 32;                 // slices per batch
constexpr int R = N / S;              // 32 rows per slice
constexpr int NBLK = B * S;           // 1024 blocks
constexpr int NTHR = 256;
constexpr int RPT = 8;                // rows per thread
constexpr int CHUNKS = 32;            // column chunks per side
constexpr int CPC = N / CHUNKS;       // 32 cols per chunk (strided: col = chunk + 32k)

// One block per (batch, slice). Fused final reduction via last-block pattern.
// side 0 (t<128): pred rows of this slice vs ALL gt cols   -> dis1 rows
// side 1 (t>=128): gt rows of this slice vs ALL pred cols  -> dis2 rows
// group = ti>>5 owns 8 rows; chunk = ti&31 owns cols {chunk + 32k}.
// Strided cols => each iter reads 512 consecutive LDS bytes (conflict-free)
// with a pure offset-immediate ds_read_b128 (no per-iter address math).
__global__ __launch_bounds__(NTHR, 4) void chamfer_fused(
    const float* __restrict__ dR,   // [B,3,3] delta_rot_pred
    const float* __restrict__ dt,   // [B,3]   delta_trans_pred
    const float* __restrict__ tc,   // [B,3]   trans_cur
    const float* __restrict__ Rc,   // [B,3,3] rot_cur
    const float* __restrict__ G,    // [B,3,3] rot_gt
    const float* __restrict__ g,    // [B,3]   trans_gt
    const float* __restrict__ pts,  // [B,N,3] points_tmp
    const float* __restrict__ sym,  // [B]     sym_flag
    float* __restrict__ partial,    // [NBLK] in d_ws
    unsigned int* __restrict__ counter, // 1 uint in d_ws (memset to 0 each call)
    float* __restrict__ out)        // [1]
{
    __shared__ float4 sp[N];          // posed_refined (pred): xyz + |a|^2
    __shared__ float4 sg[N];          // posed_gt:             xyz + |c|^2
    __shared__ float wsum[4];
    __shared__ int lastflag;

    const int blk   = blockIdx.x;
    const int b     = blk / S;
    const int slice = blk % S;
    const int t     = threadIdx.x;

    // ---- uniform per-block transform setup ----
    const float* dRb = dR + b * 9;
    const float* Rcb = Rc + b * 9;
    const float* Gb  = G  + b * 9;
    const float* dtb = dt + b * 3;
    const float* tcb = tc + b * 3;
    const float* gb  = g  + b * 3;
    const float symb = sym[b];

    // M = Rc * dR  (posed_refined = M*p + v), v = Rc*dt + tc
    float M[9], v[3];
    #pragma unroll
    for (int j = 0; j < 3; ++j) {
        #pragma unroll
        for (int i = 0; i < 3; ++i) {
            M[j*3+i] = Rcb[j*3+0] * dRb[0*3+i]
                     + Rcb[j*3+1] * dRb[1*3+i]
                     + Rcb[j*3+2] * dRb[2*3+i];
        }
        v[j] = Rcb[j*3+0] * dtb[0] + Rcb[j*3+1] * dtb[1] + Rcb[j*3+2] * dtb[2] + tcb[j];
    }

    float acc = 0.f;   // this thread's contribution to the block partial

    // ---- stage transformed points into LDS (vectorized loads, + fused l2 term) ----
    {
        const float4* P4 = (const float4*)(pts + (size_t)b * N * 3);
        const float4 A  = P4[3*t + 0];
        const float4 Bv = P4[3*t + 1];
        const float4 C  = P4[3*t + 2];
        const float px[4] = {A.x, A.w, Bv.z, C.y};
        const float py[4] = {A.y, Bv.x, Bv.w, C.z};
        const float pz[4] = {A.z, Bv.y, C.x, C.w};
        #pragma unroll
        for (int u = 0; u < 4; ++u) {
            const int i = 4*t + u;
            const float ax = M[0]*px[u] + M[1]*py[u] + M[2]*pz[u] + v[0];
            const float ay = M[3]*px[u] + M[4]*py[u] + M[5]*pz[u] + v[1];
            const float az = M[6]*px[u] + M[7]*py[u] + M[8]*pz[u] + v[2];
            const float cx = Gb[0]*px[u] + Gb[1]*py[u] + Gb[2]*pz[u] + gb[0];
            const float cy = Gb[3]*px[u] + Gb[4]*py[u] + Gb[5]*pz[u] + gb[1];
            const float cz = Gb[6]*px[u] + Gb[7]*py[u] + Gb[8]*pz[u] + gb[2];
            sp[i] = make_float4(ax, ay, az, ax*ax + ay*ay + az*az);
            sg[i] = make_float4(cx, cy, cz, cx*cx + cy*cy + cz*cz);
            if (slice == 0) {   // l2 term counted exactly once per batch
                const float dx = ax - cx, dy = ay - cy, dz = az - cz;
                acc += (1.f - symb) * sqrtf(dx*dx + dy*dy + dz*dz);
            }
        }
    }
    __syncthreads();

    // ---- per-thread row fragments (packed pairs) ----
    const int side  = t >> 7;       // 0: pred rows; 1: gt rows
    const int ti    = t & 127;
    const int chunk = ti & (CHUNKS - 1);
    const int group = ti >> 5;      // 0..3
    const int r0    = slice * R + group * RPT;

    const float4* own = side ? sg : sp;
    const float4* opp = side ? sp : sg;
    const float4* qp  = opp + chunk;      // lane's column base; cols chunk+32k

    float2 nx2[RPT/2], ny2[RPT/2], nz2[RPT/2], mins2[RPT/2];
    float p2[RPT];
    #pragma unroll
    for (int i = 0; i < RPT/2; ++i) {
        const float4 o0 = own[r0 + 2*i];
        const float4 o1 = own[r0 + 2*i + 1];
        nx2[i] = make_float2(-2.f * o0.x, -2.f * o1.x);
        ny2[i] = make_float2(-2.f * o0.y, -2.f * o1.y);
        nz2[i] = make_float2(-2.f * o0.z, -2.f * o1.z);
        p2[2*i]   = o0.w;
        p2[2*i+1] = o1.w;
        mins2[i] = make_float2(3.4e38f, 3.4e38f);
    }

    // ---- pairwise-min main loop: f = |q|^2 - 2 p.q via packed fp32 ----
    #pragma unroll 8
    for (int k = 0; k < CPC; ++k) {
        const float4 q = qp[k * CHUNKS];            // ds_read_b128 offset:k*512
        const float2 qxy = make_float2(q.x, q.y);
        const float2 qzw = make_float2(q.z, q.w);
        #pragma unroll
        for (int i = 0; i < RPT/2; ++i) {
            float2 f2;
            // f2 = nz2*q.z + q.w  (b: broadcast lo=q.z; c: broadcast hi=q.w)
            asm("v_pk_fma_f32 %0, %1, %2, %3 op_sel:[0,0,1] op_sel_hi:[1,0,1]"
                : "=v"(f2) : "v"(nz2[i]), "v"(qzw), "v"(qzw));
            // f2 += ny2*q.y  (b: broadcast hi=q.y)
            asm("v_pk_fma_f32 %0, %1, %2, %0 op_sel:[0,1,0] op_sel_hi:[1,1,1]"
                : "+v"(f2) : "v"(ny2[i]), "v"(qxy));
            // f2 += nx2*q.x  (b: broadcast lo=q.x)
            asm("v_pk_fma_f32 %0, %1, %2, %0 op_sel:[0,0,0] op_sel_hi:[1,0,1]"
                : "+v"(f2) : "v"(nx2[i]), "v"(qxy));
            mins2[i].x = fminf(mins2[i].x, f2.x);
            mins2[i].y = fminf(mins2[i].y, f2.y);
        }
    }

    // ---- reduce chunk-mins across the 32 lanes of this group ----
    float mins[RPT];
    #pragma unroll
    for (int i = 0; i < RPT/2; ++i) { mins[2*i] = mins2[i].x; mins[2*i+1] = mins2[i].y; }
    #pragma unroll
    for (int r = 0; r < RPT; ++r) {
        #pragma unroll
        for (int m = 1; m <= 16; m <<= 1)
            mins[r] = fminf(mins[r], __shfl_xor(mins[r], m));
    }
    if ((ti & 31) == 0) {
        #pragma unroll
        for (int r = 0; r < RPT; ++r) {
            const float d2 = fmaxf(mins[r] + p2[r], 0.f);
            acc += 0.5f * symb * sqrtf(d2);
        }
    }

    // ---- block sum ----
    #pragma unroll
    for (int m = 1; m <= 32; m <<= 1) acc += __shfl_xor(acc, m);
    if ((t & 63) == 0) wsum[t >> 6] = acc;
    __syncthreads();
    if (t == 0) {
        const float bsum = (wsum[0] + wsum[1]) + (wsum[2] + wsum[3]);
        __hip_atomic_store(&partial[blk], bsum, __ATOMIC_RELEASE, __HIP_MEMORY_SCOPE_AGENT);
        const unsigned old = __hip_atomic_fetch_add(counter, 1u, __ATOMIC_ACQ_REL,
                                                    __HIP_MEMORY_SCOPE_AGENT);
        lastflag = (old == (unsigned)(NBLK - 1));
    }
    __syncthreads();

    // ---- last arriving block: final reduction (deterministic fixed order) ----
    if (lastflag) {
        float a = 0.f;
        #pragma unroll
        for (int j = 0; j < NBLK / NTHR; ++j)
            a += __hip_atomic_load(&partial[t + j * NTHR], __ATOMIC_ACQUIRE,
                                   __HIP_MEMORY_SCOPE_AGENT);
        #pragma unroll
        for (int m = 1; m <= 32; m <<= 1) a += __shfl_xor(a, m);
        if ((t & 63) == 0) wsum[t >> 6] = a;
        __syncthreads();
        if (t == 0)
            out[0] = ((wsum[0] + wsum[1]) + (wsum[2] + wsum[3])) * (1.0f / (float)(B * N));
    }
}

extern "C" void kernel_launch(void* const* d_in, const int* in_sizes, int n_in,
                              void* d_out, int out_size, void* d_ws, size_t ws_size,
                              hipStream_t stream) {
    const float* dR  = (const float*)d_in[0];  // delta_rot_pred [B,3,3]
    const float* dt  = (const float*)d_in[1];  // delta_trans_pred [B,3]
    const float* tc  = (const float*)d_in[2];  // trans_cur [B,3]
    const float* Rc  = (const float*)d_in[3];  // rot_cur [B,3,3]
    const float* G   = (const float*)d_in[4];  // rot_gt [B,3,3]
    const float* g   = (const float*)d_in[5];  // trans_gt [B,3]
    const float* pts = (const float*)d_in[6];  // points_tmp [B,N,3]
    const float* sym = (const float*)d_in[7];  // sym_flag [B]

    float* partial       = (float*)d_ws;                       // NBLK floats
    unsigned int* counter = (unsigned int*)((char*)d_ws + 4096);
    float* out           = (float*)d_out;

    hipMemsetAsync(counter, 0, sizeof(unsigned int), stream);  // graph-capturable
    chamfer_fused<<<NBLK, NTHR, 0, stream>>>(dR, dt, tc, Rc, G, g, pts, sym,
                                             partial, counter, out);
}

// Round 4
// 15.175 us; speedup vs baseline: 2.9260x; 2.9260x over previous
//
#include <hip/hip_runtime.h>
#include <math.h>

// Problem constants
constexpr int B = 32;
constexpr int N = 1024;
constexpr int OCTS = 16;          // row-octets per batch (64 rows each side)
constexpr int NBLK = B * OCTS;    // 512 blocks
constexpr int NTHR = 512;         // 8 waves: 4 pred-strips + 4 gt-strips
constexpr unsigned short ONE_BF = 0x3F80;  // bf16 1.0

typedef __attribute__((ext_vector_type(8))) short short8;
typedef __attribute__((ext_vector_type(4))) float f32x4;

// bf16 hi/lo split: h = bf16_rne(x), l = bf16_rne(x - float(h))
__device__ __forceinline__ void split_bf(float x, unsigned short& h, unsigned short& l) {
    union { float f; unsigned u; } a; a.f = x;
    unsigned r = (a.u + 0x7FFFu + ((a.u >> 16) & 1u)) >> 16;
    h = (unsigned short)r;
    union { unsigned u; float f; } hb; hb.u = r << 16;
    union { float f; unsigned u; } d; d.f = x - hb.f;
    l = (unsigned short)((d.u + 0x7FFFu + ((d.u >> 16) & 1u)) >> 16);
}
// exact -2*h for bf16 bits (sign flip + exponent+1), 0-safe
__device__ __forceinline__ unsigned short neg2bf(unsigned short h) {
    return (unsigned short)((h & 0x7FFFu) ? (unsigned short)((h ^ 0x8000u) + 0x0080u)
                                          : (unsigned short)0);
}
__device__ __forceinline__ unsigned pk(unsigned short a, unsigned short b) {
    return (unsigned)a | ((unsigned)b << 16);
}

// One block per (batch, oct). Waves 0-3: pred rows (dis1); waves 4-7: gt rows (dis2).
// Each wave owns 16 rows, sweeps 64 col-tiles; one MFMA per tile yields the 16x16
// d^2 block directly (norm terms folded into K-slots); 4 fmin/tile running row-min.
__global__ __launch_bounds__(NTHR, 4) void chamfer_mfma(
    const float* __restrict__ dR,   // [B,3,3]
    const float* __restrict__ dt,   // [B,3]
    const float* __restrict__ tc,   // [B,3]
    const float* __restrict__ Rc,   // [B,3,3]
    const float* __restrict__ G,    // [B,3,3]
    const float* __restrict__ g,    // [B,3]
    const float* __restrict__ pts,  // [B,N,3]
    const float* __restrict__ sym,  // [B]
    float* __restrict__ partial)    // [NBLK]
{
    __shared__ __align__(16) unsigned short Bp[N][16];   // pred B-form (32B/pt)
    __shared__ __align__(16) unsigned short Bg[N][16];   // gt   B-form
    __shared__ __align__(16) unsigned short Ap[64][32];  // pred A-form (64B/row, hi 32B = 0)
    __shared__ __align__(16) unsigned short Ag[64][32];  // gt   A-form
    __shared__ float wsum[8];

    const int blk = blockIdx.x;
    const int b   = blk >> 4;
    const int oct = blk & 15;
    const int t   = threadIdx.x;

    // ---- uniform per-block transforms ----
    const float* dRb = dR + b * 9;
    const float* Rcb = Rc + b * 9;
    const float* Gb  = G  + b * 9;
    const float* dtb = dt + b * 3;
    const float* tcb = tc + b * 3;
    const float* gb  = g  + b * 3;
    const float symb = sym[b];

    float M[9], v[3];
    #pragma unroll
    for (int j = 0; j < 3; ++j) {
        #pragma unroll
        for (int i = 0; i < 3; ++i)
            M[j*3+i] = Rcb[j*3+0]*dRb[0*3+i] + Rcb[j*3+1]*dRb[1*3+i] + Rcb[j*3+2]*dRb[2*3+i];
        v[j] = Rcb[j*3+0]*dtb[0] + Rcb[j*3+1]*dtb[1] + Rcb[j*3+2]*dtb[2] + tcb[j];
    }

    float acc = 0.f;

    // ---- stage: 2 points per thread -> pose, split, pack to LDS ----
    {
        const float2* P2 = (const float2*)(pts + (size_t)b * N * 3);
        const float2 u0 = P2[3*t + 0];
        const float2 u1 = P2[3*t + 1];
        const float2 u2 = P2[3*t + 2];
        const float pxs[2] = {u0.x, u1.y};
        const float pys[2] = {u0.y, u2.x};
        const float pzs[2] = {u1.x, u2.y};
        #pragma unroll
        for (int s = 0; s < 2; ++s) {
            const int i = 2*t + s;
            const float px = pxs[s], py = pys[s], pz = pzs[s];
            const float ax = fmaf(M[0],px, fmaf(M[1],py, fmaf(M[2],pz, v[0])));
            const float ay = fmaf(M[3],px, fmaf(M[4],py, fmaf(M[5],pz, v[1])));
            const float az = fmaf(M[6],px, fmaf(M[7],py, fmaf(M[8],pz, v[2])));
            const float cx = fmaf(Gb[0],px, fmaf(Gb[1],py, fmaf(Gb[2],pz, gb[0])));
            const float cy = fmaf(Gb[3],px, fmaf(Gb[4],py, fmaf(Gb[5],pz, gb[1])));
            const float cz = fmaf(Gb[6],px, fmaf(Gb[7],py, fmaf(Gb[8],pz, gb[2])));
            const float a2 = ax*ax + ay*ay + az*az;
            const float c2 = cx*cx + cy*cy + cz*cz;

            if (oct == 0) {  // l2 term exactly once per batch
                const float dx = ax - cx, dy = ay - cy, dz = az - cz;
                acc += (1.f - symb) * sqrtf(dx*dx + dy*dy + dz*dz);
            }

            unsigned short axh,axl, ayh,ayl, azh,azl, anh,anl;
            unsigned short cxh,cxl, cyh,cyl, czh,czl, cnh,cnl;
            split_bf(ax,axh,axl); split_bf(ay,ayh,ayl); split_bf(az,azh,azl); split_bf(a2,anh,anl);
            split_bf(cx,cxh,cxl); split_bf(cy,cyh,cyl); split_bf(cz,czh,czl); split_bf(c2,cnh,cnl);

            // B-forms: [h,h,h, h,h,h, l,l,l, l,l,l, 1,1, n2h,n2l]
            uint4 bp0 = {pk(axh,ayh), pk(azh,axh), pk(ayh,azh), pk(axl,ayl)};
            uint4 bp1 = {pk(azl,axl), pk(ayl,azl), pk(ONE_BF,ONE_BF), pk(anh,anl)};
            *(uint4*)&Bp[i][0] = bp0; *(uint4*)&Bp[i][8] = bp1;
            uint4 bg0 = {pk(cxh,cyh), pk(czh,cxh), pk(cyh,czh), pk(cxl,cyl)};
            uint4 bg1 = {pk(czl,cxl), pk(cyl,czl), pk(ONE_BF,ONE_BF), pk(cnh,cnl)};
            *(uint4*)&Bg[i][0] = bg0; *(uint4*)&Bg[i][8] = bg1;

            // A-forms only for this oct's 64 rows:
            // [-2h(3), -2l(3), -2h(3), -2l(3), n2h,n2l, 1,1] + 16 zero slots
            if ((i >> 6) == oct) {
                const int lr = i & 63;
                const unsigned short nxh=neg2bf(axh), nyh=neg2bf(ayh), nzh=neg2bf(azh);
                const unsigned short nxl=neg2bf(axl), nyl=neg2bf(ayl), nzl=neg2bf(azl);
                uint4 a0 = {pk(nxh,nyh), pk(nzh,nxl), pk(nyl,nzl), pk(nxh,nyh)};
                uint4 a1 = {pk(nzh,nxl), pk(nyl,nzl), pk(anh,anl), pk(ONE_BF,ONE_BF)};
                uint4 zz = {0,0,0,0};
                *(uint4*)&Ap[lr][0] = a0; *(uint4*)&Ap[lr][8]  = a1;
                *(uint4*)&Ap[lr][16] = zz; *(uint4*)&Ap[lr][24] = zz;
                const unsigned short mxh=neg2bf(cxh), myh=neg2bf(cyh), mzh=neg2bf(czh);
                const unsigned short mxl=neg2bf(cxl), myl=neg2bf(cyl), mzl=neg2bf(czl);
                uint4 c0 = {pk(mxh,myh), pk(mzh,mxl), pk(myl,mzl), pk(mxh,myh)};
                uint4 c1 = {pk(mzh,mxl), pk(myl,mzl), pk(cnh,cnl), pk(ONE_BF,ONE_BF)};
                *(uint4*)&Ag[lr][0] = c0; *(uint4*)&Ag[lr][8]  = c1;
                *(uint4*)&Ag[lr][16] = zz; *(uint4*)&Ag[lr][24] = zz;
            }
        }
    }
    __syncthreads();

    // ---- MFMA sweep ----
    const int w    = t >> 6;
    const int lane = t & 63;
    const int side = w >> 2;        // 0: pred rows vs gt cols; 1: gt rows vs pred cols
    const int strip= w & 3;
    const int col  = lane & 15;
    const int kg   = lane >> 4;

    const unsigned short* Abase = (side ? &Ag[0][0] : &Ap[0][0])
                                  + (strip*16 + col) * 32 + kg * 8;
    const unsigned short* Bbase = (side ? &Bp[0][0] : &Bg[0][0])
                                  + col * 16 + (kg & 1) * 8;

    const short8 av = *(const short8*)Abase;
    const f32x4 zero = {0.f, 0.f, 0.f, 0.f};
    float r0 = 3.4e38f, r1 = 3.4e38f, r2 = 3.4e38f, r3 = 3.4e38f;

    #pragma unroll 8
    for (int tile = 0; tile < 64; ++tile) {
        const short8 bv = *(const short8*)(Bbase + tile * 256);
        const f32x4 c = __builtin_amdgcn_mfma_f32_16x16x32_bf16(av, bv, zero, 0, 0, 0);
        r0 = fminf(r0, c[0]); r1 = fminf(r1, c[1]);
        r2 = fminf(r2, c[2]); r3 = fminf(r3, c[3]);
    }

    // reduce row-mins across the 16 col-lanes
    #pragma unroll
    for (int m = 1; m <= 8; m <<= 1) {
        r0 = fminf(r0, __shfl_xor(r0, m));
        r1 = fminf(r1, __shfl_xor(r1, m));
        r2 = fminf(r2, __shfl_xor(r2, m));
        r3 = fminf(r3, __shfl_xor(r3, m));
    }
    if (col == 0) {
        acc += 0.5f * symb * (sqrtf(fmaxf(r0, 0.f)) + sqrtf(fmaxf(r1, 0.f)) +
                              sqrtf(fmaxf(r2, 0.f)) + sqrtf(fmaxf(r3, 0.f)));
    }

    // ---- block sum ----
    #pragma unroll
    for (int m = 1; m <= 32; m <<= 1) acc += __shfl_xor(acc, m);
    if (lane == 0) wsum[w] = acc;
    __syncthreads();
    if (t == 0) {
        float s = 0.f;
        #pragma unroll
        for (int j = 0; j < 8; ++j) s += wsum[j];
        partial[blk] = s;
    }
}

// Final reduction: 512 partials -> scalar mean
__global__ __launch_bounds__(128) void chamfer_final(
    const float* __restrict__ partial, float* __restrict__ out)
{
    __shared__ float wsum[2];
    const int t = threadIdx.x;
    const float4 v = ((const float4*)partial)[t];   // 128*4 = 512
    float a = (v.x + v.y) + (v.z + v.w);
    #pragma unroll
    for (int m = 1; m <= 32; m <<= 1) a += __shfl_xor(a, m);
    if ((t & 63) == 0) wsum[t >> 6] = a;
    __syncthreads();
    if (t == 0) out[0] = (wsum[0] + wsum[1]) * (1.0f / (float)(B * N));
}

extern "C" void kernel_launch(void* const* d_in, const int* in_sizes, int n_in,
                              void* d_out, int out_size, void* d_ws, size_t ws_size,
                              hipStream_t stream) {
    const float* dR  = (const float*)d_in[0];
    const float* dt  = (const float*)d_in[1];
    const float* tc  = (const float*)d_in[2];
    const float* Rc  = (const float*)d_in[3];
    const float* G   = (const float*)d_in[4];
    const float* g   = (const float*)d_in[5];
    const float* pts = (const float*)d_in[6];
    const float* sym = (const float*)d_in[7];

    float* partial = (float*)d_ws;     // NBLK floats
    float* out     = (float*)d_out;

    chamfer_mfma<<<NBLK, NTHR, 0, stream>>>(dR, dt, tc, Rc, G, g, pts, sym, partial);
    chamfer_final<<<1, 128, 0, stream>>>(partial, out);
}